// Round 7
// baseline (264.856 us; speedup 1.0000x reference)
//
#include <hip/hip_runtime.h>
#include <hip/hip_bf16.h>
#include <math.h>

// PCNN fused: Conv1d(k=3,pad=1) -> masked piecewise max-pool -> tanh
// R15: occupancy push. Wave tile halved along N (64l x 32h):
//  - acc[4][2] = 32 AGPR, bb[2][2] = 16 VGPR -> target <=85 regs/wave
//    => 6 waves/SIMD = 24 waves/CU = 3 blocks/CU (launch_bounds(512,6)).
//  - Block covers N=128: 2 blocks per batch (R10 N-split decode, the two
//    halves of a batch paired on one XCD so the duplicated X stage hits L2).
//  - Session scaling law: perf ~ resident waves (R13 8w:167, R10/12 16w:97-134).
//    This buys +50% TLP for the price of one extra X stage per batch.
//  - K-loop / staging math / halo remap / epilogue logic identical to R12
//    (96.7us verified); prologue staging split 3+2 to cap prologue VGPR.

#define B_SZ   2048
#define L_SEQ  128
#define C_INCH 150
#define H_OUT  230
#define RS     152      // row stride in bf16 (304 B); 152 = 19*8
#define NROW   129      // rows l=-1..127; l=128 halo remapped to row 0 (both zero)
#define NS8    2451     // short8s per tile = NROW*RS/8

typedef __attribute__((ext_vector_type(8))) short short8;   // 8 bf16
typedef __attribute__((ext_vector_type(4))) float float4v;  // mfma acc

static __device__ __forceinline__ unsigned short f2bf(float f) {
    union { float f; unsigned u; } x{f};
    unsigned r = (x.u + 0x7FFFu + ((x.u >> 16) & 1u)) >> 16;  // RNE
    return (unsigned short)r;
}

static __device__ __forceinline__ unsigned cvt2(float2 f) {
    __hip_bfloat162 h = __float22bfloat162_rn(f);   // v_cvt_pk_bf16_f32
    union { __hip_bfloat162 h; unsigned u; } c{h};
    return c.u;
}

static __device__ __forceinline__ float tanh_fast_pos(float v) {
    float e = __expf(2.0f * v);
    return 1.0f - 2.0f / (e + 1.0f);
}

// Staging helpers (verified R11-R14 math, 512-thread indexing):
// t = it*512+tid indexes short8s; row = t/19 (l = row-1), j = t%19.
static __device__ __forceinline__ void stage_load(const float* __restrict__ xb,
                                                  int tid, int it, float2 pl[4]) {
    const int t   = it * 512 + tid;
    const int tc  = (t < NS8) ? t : (NS8 - 1);
    const int row = tc / 19;
    const int j   = tc - row * 19;
    const int rm1 = (row > 0) ? (row - 1) : 0;
    const float* s = xb + rm1 * C_INCH + j * 8;
    pl[0] = *(const float2*)(s);
    pl[1] = *(const float2*)(s + 2);
    pl[2] = *(const float2*)(s + 4);
    pl[3] = *(const float2*)(s + ((j < 18) ? 6 : 4));   // j=18 dup, zeroed later
}

static __device__ __forceinline__ void stage_write(unsigned short* __restrict__ dst,
                                                   int tid, int it, const float2 pl[4]) {
    const int t   = it * 512 + tid;
    const int tc  = (t < NS8) ? t : (NS8 - 1);
    const int row = tc / 19;
    const int j   = tc - row * 19;
    uint4 u;
    u.x = cvt2(pl[0]); u.y = cvt2(pl[1]); u.z = cvt2(pl[2]); u.w = cvt2(pl[3]);
    const bool z = (row == 0);                 // halo row -> zeros
    u.x = z ? 0u : u.x;
    u.y = z ? 0u : u.y;
    u.z = z ? 0u : u.z;
    u.w = (z || j == 18) ? 0u : u.w;           // pad cols 150,151 -> zero
    if (t < NS8) *(uint4*)(dst + (size_t)t * 8) = u;
}

// Pack W[h][c][k] fp32 -> Wpk fragment order (verified R4-R14):
//   kk = k*5+kc, ht = h/16, lane = q*16+c15
//   Wpk[((kk*16+ht)*64+lane)*8 + e] = bf16(W[ht*16+c15][kc*32+q*8+e][k])
__global__ void pack_w_kernel(const float* __restrict__ W,
                              unsigned short* __restrict__ Wpk) {
    int t = blockIdx.x * 256 + threadIdx.x;       // < 15360
    int kk   = t >> 10;
    int rem  = t & 1023;
    int ht   = rem >> 6;
    int lane = rem & 63;
    int q    = lane >> 4;
    int c15  = lane & 15;
    int k    = kk / 5;
    int kc   = kk - k * 5;
    int h    = ht * 16 + c15;
    int cb   = kc * 32 + q * 8;
    unsigned short v[8];
    #pragma unroll
    for (int e = 0; e < 8; ++e) {
        int c = cb + e;
        float f = (h < H_OUT && c < C_INCH) ? W[h * 450 + c * 3 + k] : 0.0f;
        v[e] = f2bf(f);
    }
    *(short8*)(Wpk + (size_t)t * 8) = *(short8*)v;
}

__global__ void __launch_bounds__(512, 6)
pcnn_mfma(const float* __restrict__ Xea, const int* __restrict__ Xmask,
          const unsigned short* __restrict__ Wpk,
          const float* __restrict__ bias, float* __restrict__ out) {
    __shared__ __align__(16) unsigned short sX[NROW * RS];   // 39216 B
    __shared__ __align__(16) float sSel[L_SEQ * 3];          // 1536 B (tot 40752)

    const int tid  = threadIdx.x;
    const int wv   = tid >> 6;        // 0..7
    const int lane = tid & 63;
    const int q    = lane >> 4;
    const int c15  = lane & 15;
    const int mh   = wv & 1;          // m-half: l offset 64*mh
    const int nq   = wv >> 1;         // n-quarter within block half: 32*nq

    // batch / n-half decode: pair the two halves of a batch on one XCD
    // (g = xcd + 8*(2*loc + nbh)) -> duplicated X stage hits that XCD's L2.
    const int g    = blockIdx.x;
    const int xcd  = g & 7;
    const int rest = g >> 3;          // 0..511
    const int b    = xcd * 256 + (rest >> 1);
    const int nbh  = rest & 1;        // H-half: 0 -> h 0..127, 1 -> h 128..229

    // B pointer: h-tile base ht0 = nbh*8 + nq*2; frags nj in {0,1} at +nj*512
    const unsigned short* wp =
        Wpk + ((size_t)((nbh * 8 + nq * 2) * 64) + lane) * 8;

    // ---- preload B chunk 0 into set 0 ----
    short8 bb[2][2];
    #pragma unroll
    for (int nj = 0; nj < 2; ++nj)
        bb[0][nj] = *(const short8*)(wp + nj * 512);

    // ---- X staging: branch-free, 3+2 split (prologue VGPR cap) ----
    const float* xb = Xea + (size_t)b * (L_SEQ * C_INCH);
    {
        float2 pl[3][4];
        #pragma unroll
        for (int it = 0; it < 3; ++it) stage_load(xb, tid, it, pl[it]);
        if (tid < L_SEQ) {
            int mv = Xmask[(size_t)b * L_SEQ + tid];
            sSel[tid * 3 + 0] = (mv == 1) ? 0.0f : -1e30f;
            sSel[tid * 3 + 1] = (mv == 2) ? 0.0f : -1e30f;
            sSel[tid * 3 + 2] = (mv == 3) ? 0.0f : -1e30f;
        }
        #pragma unroll
        for (int it = 0; it < 3; ++it) stage_write(sX, tid, it, pl[it]);
        #pragma unroll
        for (int it = 0; it < 2; ++it) stage_load(xb, tid, 3 + it, pl[it]);
        #pragma unroll
        for (int it = 0; it < 2; ++it) stage_write(sX, tid, 3 + it, pl[it]);
    }

    __syncthreads();   // X tile ready; only barrier before the epilogue

    // ---- MFMA: 15 K-chunks of 32; B in registers, alternating sets ----
    float4v acc[4][2];
    #pragma unroll
    for (int mi = 0; mi < 4; ++mi)
        #pragma unroll
        for (int nj = 0; nj < 2; ++nj)
            acc[mi][nj] = (float4v){0.f, 0.f, 0.f, 0.f};

    const unsigned short* a0p = sX + (mh * 64 + c15) * RS + q * 8;
    // l=128 halo: row mh*64+c15+mi*16+k == 129 only at (mh=1,mi=3,c15=15,k=2);
    // remap to row 0 (zeros).
    const unsigned short* a3p2 = (mh == 1 && c15 == 15) ? (a0p - 129 * RS) : a0p;

    #pragma unroll
    for (int kk = 0; kk < 15; ++kk) {
        const int cur = kk & 1;
        // issue next chunk's B loads (consumed after this chunk's MFMAs)
        if (kk < 14) {
            #pragma unroll
            for (int nj = 0; nj < 2; ++nj)
                bb[cur ^ 1][nj] =
                    *(const short8*)(wp + (size_t)(kk + 1) * 8192 + nj * 512);
        }
        const int k  = kk / 5;
        const int kc = kk - k * 5;
        short8 a[4];
        #pragma unroll
        for (int mi = 0; mi < 4; ++mi) {
            const unsigned short* base = (mi == 3 && k == 2) ? a3p2 : a0p;
            a[mi] = *(const short8*)(base + (mi * 16 + k) * RS + kc * 32);
        }
        __builtin_amdgcn_s_setprio(1);
        #pragma unroll
        for (int mi = 0; mi < 4; ++mi)
            #pragma unroll
            for (int nj = 0; nj < 2; ++nj)
                acc[mi][nj] = __builtin_amdgcn_mfma_f32_16x16x32_bf16(
                    a[mi], bb[cur][nj], acc[mi][nj], 0, 0, 0);
        __builtin_amdgcn_s_setprio(0);
        __builtin_amdgcn_sched_barrier(0);
    }

    // ---- Epilogue: selector-add masked max (bias deferred) ----
    // C/D layout: col(h)=c15, row(l in frag)=q*4+r
    float pz[2][3];
    #pragma unroll
    for (int nj = 0; nj < 2; ++nj)
        #pragma unroll
        for (int p = 0; p < 3; ++p) pz[nj][p] = -1e30f;

    #pragma unroll
    for (int mi = 0; mi < 4; ++mi) {
        const int l0 = mh * 64 + mi * 16 + q * 4;            // mult of 4
        const float4v* sp = (const float4v*)(sSel + l0 * 3); // 48B, 16B-aligned
        const float4v s0 = sp[0], s1 = sp[1], s2 = sp[2];
        const float sl[12] = {s0.x, s0.y, s0.z, s0.w, s1.x, s1.y,
                              s1.z, s1.w, s2.x, s2.y, s2.z, s2.w};
        #pragma unroll
        for (int nj = 0; nj < 2; ++nj)
            #pragma unroll
            for (int r = 0; r < 4; ++r) {
                const float y = acc[mi][nj][r];
                pz[nj][0] = fmaxf(pz[nj][0], y + sl[r * 3 + 0]);
                pz[nj][1] = fmaxf(pz[nj][1], y + sl[r * 3 + 1]);
                pz[nj][2] = fmaxf(pz[nj][2], y + sl[r * 3 + 2]);
            }
    }

    __syncthreads();   // all sX reads done -> alias partials onto sX
    float* sP = (float*)sX;   // [mh][hl 0..127][3] = 768 floats

    #pragma unroll
    for (int nj = 0; nj < 2; ++nj) {
        float p0 = pz[nj][0], p1 = pz[nj][1], p2 = pz[nj][2];
        p0 = fmaxf(p0, __shfl_xor(p0, 16, 64));
        p1 = fmaxf(p1, __shfl_xor(p1, 16, 64));
        p2 = fmaxf(p2, __shfl_xor(p2, 16, 64));
        p0 = fmaxf(p0, __shfl_xor(p0, 32, 64));
        p1 = fmaxf(p1, __shfl_xor(p1, 32, 64));
        p2 = fmaxf(p2, __shfl_xor(p2, 32, 64));
        if (q == 0) {
            const int hl = nq * 32 + nj * 16 + c15;          // 0..127
            float* d = sP + (mh * 128 + hl) * 3;
            d[0] = p0; d[1] = p1; d[2] = p2;
        }
    }
    __syncthreads();

    // Combine m-halves, add bias, clamp 0, tanh, store (this block's H-half)
    for (int t = tid; t < 384; t += 512) {
        const int hl = t / 3;
        const int p  = t - hl * 3;
        const int h  = nbh * 128 + hl;
        if (h < H_OUT) {
            float v = fmaxf(sP[hl * 3 + p], sP[(128 + hl) * 3 + p]);
            v = fmaxf(0.0f, v + bias[h]);
            out[(size_t)b * (3 * H_OUT) + h * 3 + p] = tanh_fast_pos(v);
        }
    }
}

extern "C" void kernel_launch(void* const* d_in, const int* in_sizes, int n_in,
                              void* d_out, int out_size, void* d_ws, size_t ws_size,
                              hipStream_t stream) {
    const float* Xea   = (const float*)d_in[0];   // [2048,128,150] f32
    const int*   Xmask = (const int*)d_in[1];     // [2048,128] i32
    const float* W     = (const float*)d_in[2];   // [230,150,3] f32
    const float* bias  = (const float*)d_in[3];   // [230] f32
    float* out = (float*)d_out;                   // [2048,690] f32
    unsigned short* Wpk = (unsigned short*)d_ws;  // 245760 B

    pack_w_kernel<<<60, 256, 0, stream>>>(W, Wpk);
    pcnn_mfma<<<B_SZ * 2, 512, 0, stream>>>(Xea, Xmask, Wpk, bias, out);
}